// Round 1
// baseline (34.127 us; speedup 1.0000x reference)
//
#include <hip/hip_runtime.h>

// Problem constants (match reference)
#define B_ROWS   256
#define L_COLS   65536
#define SLICES   16
#define THREADS  256

// Per row: V = L/4 = 16384 float4; per slice: 1024 float4; per thread: 4 iters.

__global__ __launch_bounds__(THREADS)
void signal_loss_partials(const float4* __restrict__ pred,
                          const float4* __restrict__ trgt,
                          float* __restrict__ ws)
{
    const int row   = blockIdx.x;   // 0..255
    const int slice = blockIdx.y;   // 0..15
    const int V         = L_COLS / 4;     // 16384 float4 per row
    const int per_slice = V / SLICES;     // 1024 float4 per slice
    const size_t base = (size_t)row * V + (size_t)slice * per_slice;

    float sp = 0.f, st = 0.f, spp = 0.f, stt = 0.f, spt = 0.f, sd2 = 0.f;
    for (int i = threadIdx.x; i < per_slice; i += THREADS) {
        const float4 p = pred[base + i];
        const float4 t = trgt[base + i];
        sp  += p.x + p.y + p.z + p.w;
        st  += t.x + t.y + t.z + t.w;
        spp += p.x*p.x + p.y*p.y + p.z*p.z + p.w*p.w;
        stt += t.x*t.x + t.y*t.y + t.z*t.z + t.w*t.w;
        spt += p.x*t.x + p.y*t.y + p.z*t.z + p.w*t.w;
        const float dx = p.x - t.x, dy = p.y - t.y, dz = p.z - t.z, dw = p.w - t.w;
        sd2 += dx*dx + dy*dy + dz*dz + dw*dw;
    }

    // Wave-64 butterfly-style reduce via shfl_down
    #pragma unroll
    for (int off = 32; off >= 1; off >>= 1) {
        sp  += __shfl_down(sp,  off);
        st  += __shfl_down(st,  off);
        spp += __shfl_down(spp, off);
        stt += __shfl_down(stt, off);
        spt += __shfl_down(spt, off);
        sd2 += __shfl_down(sd2, off);
    }

    __shared__ float red[4][6];
    const int lane = threadIdx.x & 63;
    const int wave = threadIdx.x >> 6;
    if (lane == 0) {
        red[wave][0] = sp;  red[wave][1] = st;  red[wave][2] = spp;
        red[wave][3] = stt; red[wave][4] = spt; red[wave][5] = sd2;
    }
    __syncthreads();
    if (threadIdx.x == 0) {
        float* dst = ws + (size_t)(row * SLICES + slice) * 6;
        #pragma unroll
        for (int k = 0; k < 6; ++k)
            dst[k] = red[0][k] + red[1][k] + red[2][k] + red[3][k];
    }
}

__global__ __launch_bounds__(B_ROWS)
void signal_loss_finalize(const float* __restrict__ ws,
                          float* __restrict__ out)
{
    const int row = threadIdx.x;  // one thread per row, 256 threads

    double s0 = 0.0, s1 = 0.0, s2 = 0.0, s3 = 0.0, s4 = 0.0, s5 = 0.0;
    for (int sl = 0; sl < SLICES; ++sl) {
        const float* src = ws + (size_t)(row * SLICES + sl) * 6;
        s0 += (double)src[0];  // sum p
        s1 += (double)src[1];  // sum t
        s2 += (double)src[2];  // sum p^2
        s3 += (double)src[3];  // sum t^2
        s4 += (double)src[4];  // sum p*t
        s5 += (double)src[5];  // sum (p-t)^2
    }

    const double n = (double)L_COLS;
    const double num   = s4 - s0 * s1 / n;        // sum(xm*ym)
    const double den_t = s3 - s1 * s1 / n;        // sum(xm^2), xm from y_true
    const double den_p = s2 - s0 * s0 / n;        // sum(ym^2), ym from y_pred
    double den = sqrt(den_t * den_p);
    den = den > 1e-8 ? den : 1e-8;
    const double one_minus_r = 1.0 - num / den;

    __shared__ double romr[B_ROWS];
    __shared__ double rsqd[B_ROWS];
    romr[row] = one_minus_r;
    rsqd[row] = s5;
    __syncthreads();
    for (int stride = B_ROWS / 2; stride >= 1; stride >>= 1) {
        if (row < stride) {
            romr[row] += romr[row + stride];
            rsqd[row] += rsqd[row + stride];
        }
        __syncthreads();
    }
    if (row == 0) {
        const double mse  = rsqd[0] / ((double)B_ROWS * (double)L_COLS);
        const double corr = romr[0] / (double)B_ROWS;
        out[0] = (float)(0.7 * mse + 0.3 * corr);
    }
}

extern "C" void kernel_launch(void* const* d_in, const int* in_sizes, int n_in,
                              void* d_out, int out_size, void* d_ws, size_t ws_size,
                              hipStream_t stream) {
    const float4* pred = (const float4*)d_in[0];  // y_pred
    const float4* trgt = (const float4*)d_in[1];  // y_true
    float* ws  = (float*)d_ws;                    // 256*16*6*4 = 96 KiB partials
    float* out = (float*)d_out;

    dim3 grid(B_ROWS, SLICES);
    signal_loss_partials<<<grid, THREADS, 0, stream>>>(pred, trgt, ws);
    signal_loss_finalize<<<1, B_ROWS, 0, stream>>>(ws, out);
}

// Round 2
// 33.345 us; speedup vs baseline: 1.0234x; 1.0234x over previous
//
#include <hip/hip_runtime.h>

// Problem constants (match reference)
#define B_ROWS   256
#define L_COLS   65536
#define SLICES   16
#define THREADS  256

// Per row: 16384 float4; per slice: 1024 float4; per thread: exactly 4 float4
// per input, loaded as one batch of 8 global_load_dwordx4 (128 B/lane in
// flight) so HBM latency is covered by MLP, not just occupancy.

__global__ __launch_bounds__(THREADS)
void signal_loss_partials(const float4* __restrict__ pred,
                          const float4* __restrict__ trgt,
                          float* __restrict__ ws)
{
    const int row   = blockIdx.x;   // 0..255
    const int slice = blockIdx.y;   // 0..15
    const size_t base = (size_t)row * (L_COLS / 4)
                      + (size_t)slice * (L_COLS / 4 / SLICES)
                      + threadIdx.x;
    const float4* P = pred + base;
    const float4* T = trgt + base;

    // Issue all 8 loads before any use.
    const float4 p0 = P[0 * THREADS];
    const float4 p1 = P[1 * THREADS];
    const float4 p2 = P[2 * THREADS];
    const float4 p3 = P[3 * THREADS];
    const float4 t0 = T[0 * THREADS];
    const float4 t1 = T[1 * THREADS];
    const float4 t2 = T[2 * THREADS];
    const float4 t3 = T[3 * THREADS];

    float sp = 0.f, st = 0.f, spp = 0.f, stt = 0.f, spt = 0.f, sd2 = 0.f;
    #define ACC(p, t)                                                       \
    do {                                                                    \
        sp  += p.x + p.y + p.z + p.w;                                       \
        st  += t.x + t.y + t.z + t.w;                                       \
        spp += p.x*p.x + p.y*p.y + p.z*p.z + p.w*p.w;                       \
        stt += t.x*t.x + t.y*t.y + t.z*t.z + t.w*t.w;                       \
        spt += p.x*t.x + p.y*t.y + p.z*t.z + p.w*t.w;                       \
        { const float dx = p.x - t.x, dy = p.y - t.y,                       \
                      dz = p.z - t.z, dw = p.w - t.w;                       \
          sd2 += dx*dx + dy*dy + dz*dz + dw*dw; }                           \
    } while (0)
    ACC(p0, t0); ACC(p1, t1); ACC(p2, t2); ACC(p3, t3);
    #undef ACC

    // Wave-64 reduce via shfl_down
    #pragma unroll
    for (int off = 32; off >= 1; off >>= 1) {
        sp  += __shfl_down(sp,  off);
        st  += __shfl_down(st,  off);
        spp += __shfl_down(spp, off);
        stt += __shfl_down(stt, off);
        spt += __shfl_down(spt, off);
        sd2 += __shfl_down(sd2, off);
    }

    __shared__ float red[4][6];
    const int lane = threadIdx.x & 63;
    const int wave = threadIdx.x >> 6;
    if (lane == 0) {
        red[wave][0] = sp;  red[wave][1] = st;  red[wave][2] = spp;
        red[wave][3] = stt; red[wave][4] = spt; red[wave][5] = sd2;
    }
    __syncthreads();
    if (threadIdx.x == 0) {
        float* dst = ws + (size_t)(row * SLICES + slice) * 6;
        #pragma unroll
        for (int k = 0; k < 6; ++k)
            dst[k] = red[0][k] + red[1][k] + red[2][k] + red[3][k];
    }
}

__global__ __launch_bounds__(B_ROWS)
void signal_loss_finalize(const float* __restrict__ ws,
                          float* __restrict__ out)
{
    const int row = threadIdx.x;  // one thread per row, 256 threads

    double s0 = 0.0, s1 = 0.0, s2 = 0.0, s3 = 0.0, s4 = 0.0, s5 = 0.0;
    #pragma unroll
    for (int sl = 0; sl < SLICES; ++sl) {
        const float* src = ws + (size_t)(row * SLICES + sl) * 6;
        s0 += (double)src[0];  // sum p
        s1 += (double)src[1];  // sum t
        s2 += (double)src[2];  // sum p^2
        s3 += (double)src[3];  // sum t^2
        s4 += (double)src[4];  // sum p*t
        s5 += (double)src[5];  // sum (p-t)^2
    }

    const double n = (double)L_COLS;
    const double num   = s4 - s0 * s1 / n;        // sum(xm*ym)
    const double den_t = s3 - s1 * s1 / n;        // sum(xm^2), xm from y_true
    const double den_p = s2 - s0 * s0 / n;        // sum(ym^2), ym from y_pred
    double den = sqrt(den_t * den_p);
    den = den > 1e-8 ? den : 1e-8;
    double romr = 1.0 - num / den;                // 1 - r for this row
    double sd   = s5;

    // Wave-64 reduce on doubles, then 4 wave partials via LDS (one barrier).
    #pragma unroll
    for (int off = 32; off >= 1; off >>= 1) {
        romr += __shfl_down(romr, off);
        sd   += __shfl_down(sd,   off);
    }
    __shared__ double w0[4], w1[4];
    const int lane = threadIdx.x & 63;
    const int wave = threadIdx.x >> 6;
    if (lane == 0) { w0[wave] = romr; w1[wave] = sd; }
    __syncthreads();
    if (threadIdx.x == 0) {
        const double corr = (w0[0] + w0[1] + w0[2] + w0[3]) / (double)B_ROWS;
        const double mse  = (w1[0] + w1[1] + w1[2] + w1[3])
                          / ((double)B_ROWS * (double)L_COLS);
        out[0] = (float)(0.7 * mse + 0.3 * corr);
    }
}

extern "C" void kernel_launch(void* const* d_in, const int* in_sizes, int n_in,
                              void* d_out, int out_size, void* d_ws, size_t ws_size,
                              hipStream_t stream) {
    const float4* pred = (const float4*)d_in[0];  // y_pred
    const float4* trgt = (const float4*)d_in[1];  // y_true
    float* ws  = (float*)d_ws;                    // 256*16*6*4 = 96 KiB partials
    float* out = (float*)d_out;

    dim3 grid(B_ROWS, SLICES);
    signal_loss_partials<<<grid, THREADS, 0, stream>>>(pred, trgt, ws);
    signal_loss_finalize<<<1, B_ROWS, 0, stream>>>(ws, out);
}